// Round 1
// baseline (133.764 us; speedup 1.0000x reference)
//
#include <hip/hip_runtime.h>

// LSTM classifier single step: B=65536, IN=64, H=128, OUT=2.
// Strategy: bias kernel folds bx + h0@Wh.T into ws; main kernel does the
// 4-gate x@Wx.T with bf16 MFMA (16x16x32), fused elementwise + OUT=2
// projection, all in one pass over x and c0 (HBM-bound, ~51 MB).

#define B_SIZE 65536

typedef __bf16 bf16x8 __attribute__((ext_vector_type(8)));
typedef __bf16 bf16x4 __attribute__((ext_vector_type(4)));
typedef float f32x4 __attribute__((ext_vector_type(4)));

__device__ __forceinline__ float fsig(float x) {
    float e = __builtin_amdgcn_exp2f(-1.442695040888963f * x);
    return __builtin_amdgcn_rcpf(1.0f + e);
}
__device__ __forceinline__ float ftanh(float x) {
    float e = __builtin_amdgcn_exp2f(2.885390081777927f * x);
    return 1.0f - 2.0f * __builtin_amdgcn_rcpf(e + 1.0f);
}

// bias512[g*128+r] = bx_g[r] + sum_k h0[k] * Wh_g[r][k]
__global__ void bias_kernel(const float* __restrict__ h0,
                            const float* __restrict__ Whf, const float* __restrict__ Whi,
                            const float* __restrict__ Who, const float* __restrict__ Whc,
                            const float* __restrict__ bxf, const float* __restrict__ bxi,
                            const float* __restrict__ bxo, const float* __restrict__ bxc,
                            float* __restrict__ bias512) {
    int j = blockIdx.x * 64 + threadIdx.x;   // 8 blocks x 64 threads = 512
    int g = j >> 7, r = j & 127;
    const float* Wh = (g == 0) ? Whf : (g == 1) ? Whi : (g == 2) ? Who : Whc;
    const float* bx = (g == 0) ? bxf : (g == 1) ? bxi : (g == 2) ? bxo : bxc;
    float s = bx[r];
    const float* row = Wh + r * 128;
#pragma unroll 8
    for (int k = 0; k < 128; ++k) s += h0[k] * row[k];
    bias512[j] = s;
}

__launch_bounds__(256, 2)
__global__ void lstm_kernel(const float* __restrict__ x, const float* __restrict__ c0,
                            const float* __restrict__ Wxf, const float* __restrict__ Wxi,
                            const float* __restrict__ Wxo, const float* __restrict__ Wxc,
                            const float* __restrict__ Wy, const float* __restrict__ by,
                            const float* __restrict__ bias512, float* __restrict__ out) {
    __shared__ __bf16 xs[1024];          // 16 rows x 64 k of x, A-fragment layout
    __shared__ float yred[4][16][2];     // per-wave partial y

    const int tid  = threadIdx.x;
    const int lane = tid & 63;
    const int w    = tid >> 6;           // wave 0..3 -> hidden cols [w*32, w*32+32)
    const int q    = lane >> 4;          // quad: rows q*4..q*4+3 of the 16-row tile
    const int n15  = lane & 15;          // col within 16-col tile

    // ---- prologue: per-wave weight fragments (held in registers all kernel) ----
    const float* Wxg[4] = {Wxf, Wxi, Wxo, Wxc};
    bf16x8 bw[4][2][2];                  // [gate][colblock][kstep]
    float biasv[4][2];
#pragma unroll
    for (int g = 0; g < 4; ++g) {
#pragma unroll
        for (int cb = 0; cb < 2; ++cb) {
            const int n = w * 32 + cb * 16 + n15;    // hidden unit index
            biasv[g][cb] = bias512[g * 128 + n];
#pragma unroll
            for (int kb = 0; kb < 2; ++kb) {
                // B[k][n] = Wx_g[n][k]; lane holds k = kb*32 + q*8 + j
                const float* p = Wxg[g] + n * 64 + kb * 32 + q * 8;
                float4 lo = *(const float4*)p;
                float4 hi = *(const float4*)(p + 4);
                bf16x8 v;
                v[0] = (__bf16)lo.x; v[1] = (__bf16)lo.y; v[2] = (__bf16)lo.z; v[3] = (__bf16)lo.w;
                v[4] = (__bf16)hi.x; v[5] = (__bf16)hi.y; v[6] = (__bf16)hi.z; v[7] = (__bf16)hi.w;
                bw[g][cb][kb] = v;
            }
        }
    }
    float wyv[2][2];
#pragma unroll
    for (int o = 0; o < 2; ++o)
#pragma unroll
        for (int cb = 0; cb < 2; ++cb)
            wyv[o][cb] = Wy[o * 128 + w * 32 + cb * 16 + n15];
    const float by0 = by[0], by1 = by[1];

    constexpr int ITERS = (B_SIZE / 16) / 512;   // 8 tiles of 16 rows per block
    const int tile0 = blockIdx.x * ITERS;        // contiguous 128 rows per block

    // x staging: thread t loads float4 of row (t>>4), k4=(t&15)*4 ; LDS index in
    // A-frag order: elem(m,k) -> (k>>5)*512 + ((k&31)>>3)*128 + m*8 + (k&7)
    const int xrow = tid >> 4;
    const int k4   = (tid & 15) * 4;
    const int sidx = (k4 >> 5) * 512 + ((k4 & 31) >> 3) * 128 + xrow * 8 + (k4 & 7);

    float4 xr = *(const float4*)(x + (size_t)(tile0 * 16 + xrow) * 64 + k4);
    {
        bf16x4 v; v[0] = (__bf16)xr.x; v[1] = (__bf16)xr.y; v[2] = (__bf16)xr.z; v[3] = (__bf16)xr.w;
        *(bf16x4*)&xs[sidx] = v;
    }
    __syncthreads();

    for (int it = 0; it < ITERS; ++it) {
        const int tile = tile0 + it;
        const int b0 = tile * 16;

        // A fragments (shared by all 4 waves)
        bf16x8 a0 = *(const bf16x8*)&xs[lane * 8];
        bf16x8 a1 = *(const bf16x8*)&xs[512 + lane * 8];

        // prefetch next x tile into registers
        const int tn = (it + 1 < ITERS) ? (tile + 1) : tile;
        xr = *(const float4*)(x + (size_t)(tn * 16 + xrow) * 64 + k4);

        // c0 gather: lane needs (row q*4+r, col w*32+cb*16+n15)
        float c0v[2][4];
#pragma unroll
        for (int cb = 0; cb < 2; ++cb)
#pragma unroll
            for (int r = 0; r < 4; ++r)
                c0v[cb][r] = c0[(size_t)(b0 + q * 4 + r) * 128 + w * 32 + cb * 16 + n15];

        // MFMA: acc initialized with bias (bias depends only on col)
        f32x4 acc[4][2];
#pragma unroll
        for (int g = 0; g < 4; ++g)
#pragma unroll
            for (int cb = 0; cb < 2; ++cb) {
                float b = biasv[g][cb];
                f32x4 t = {b, b, b, b};
                acc[g][cb] = t;
            }
#pragma unroll
        for (int g = 0; g < 4; ++g)
#pragma unroll
            for (int cb = 0; cb < 2; ++cb) {
                acc[g][cb] = __builtin_amdgcn_mfma_f32_16x16x32_bf16(a0, bw[g][cb][0], acc[g][cb], 0, 0, 0);
                acc[g][cb] = __builtin_amdgcn_mfma_f32_16x16x32_bf16(a1, bw[g][cb][1], acc[g][cb], 0, 0, 0);
            }

        // elementwise epilogue; C/D layout: col=lane&15, row=q*4+reg
        float p0[4] = {0.f, 0.f, 0.f, 0.f};
        float p1[4] = {0.f, 0.f, 0.f, 0.f};
#pragma unroll
        for (int cb = 0; cb < 2; ++cb)
#pragma unroll
            for (int r = 0; r < 4; ++r) {
                float fg = fsig(acc[0][cb][r]);
                float ig = fsig(acc[1][cb][r]);
                float og = fsig(acc[2][cb][r]);
                float ct = ftanh(acc[3][cb][r]);
                float c  = fg * c0v[cb][r] + ig * ct;
                float h  = og * ftanh(c);
                p0[r] += h * wyv[0][cb];
                p1[r] += h * wyv[1][cb];
            }
        // reduce over the 16 lanes of each quad group (cols of this wave)
#pragma unroll
        for (int m = 1; m < 16; m <<= 1) {
#pragma unroll
            for (int r = 0; r < 4; ++r) {
                p0[r] += __shfl_xor(p0[r], m, 64);
                p1[r] += __shfl_xor(p1[r], m, 64);
            }
        }
        if (n15 == 0) {
#pragma unroll
            for (int r = 0; r < 4; ++r) {
                yred[w][q * 4 + r][0] = p0[r];
                yred[w][q * 4 + r][1] = p1[r];
            }
        }
        __syncthreads();
        if (tid < 32) {
            int row = tid >> 1, o = tid & 1;
            float s = (o ? by1 : by0) + yred[0][row][o] + yred[1][row][o] +
                      yred[2][row][o] + yred[3][row][o];
            out[(size_t)(b0 + row) * 2 + o] = s;
        }
        // stage next tile (xs fully consumed before barrier above)
        {
            bf16x4 v; v[0] = (__bf16)xr.x; v[1] = (__bf16)xr.y; v[2] = (__bf16)xr.z; v[3] = (__bf16)xr.w;
            *(bf16x4*)&xs[sidx] = v;
        }
        __syncthreads();
    }
}

extern "C" void kernel_launch(void* const* d_in, const int* in_sizes, int n_in,
                              void* d_out, int out_size, void* d_ws, size_t ws_size,
                              hipStream_t stream) {
    // setup_inputs order: x, h0, c0, [Wxf,bxf,Whf], [Wxi,bxi,Whi], [Wxo,bxo,Who],
    //                     [Wxc,bxc,Whc], Wy, by
    const float* x   = (const float*)d_in[0];
    const float* h0  = (const float*)d_in[1];
    const float* c0  = (const float*)d_in[2];
    const float* Wxf = (const float*)d_in[3];
    const float* bxf = (const float*)d_in[4];
    const float* Whf = (const float*)d_in[5];
    const float* Wxi = (const float*)d_in[6];
    const float* bxi = (const float*)d_in[7];
    const float* Whi = (const float*)d_in[8];
    const float* Wxo = (const float*)d_in[9];
    const float* bxo = (const float*)d_in[10];
    const float* Who = (const float*)d_in[11];
    const float* Wxc = (const float*)d_in[12];
    const float* bxc = (const float*)d_in[13];
    const float* Whc = (const float*)d_in[14];
    const float* Wy  = (const float*)d_in[15];
    const float* by  = (const float*)d_in[16];
    float* out = (float*)d_out;
    float* bias512 = (float*)d_ws;   // 512 floats scratch

    bias_kernel<<<8, 64, 0, stream>>>(h0, Whf, Whi, Who, Whc, bxf, bxi, bxo, bxc, bias512);
    lstm_kernel<<<512, 256, 0, stream>>>(x, c0, Wxf, Wxi, Wxo, Wxc, Wy, by, bias512, out);
}